// Round 1
// baseline (199.791 us; speedup 1.0000x reference)
//
#include <hip/hip_runtime.h>
#include <hip/hip_bf16.h>
#include <cstdint>

// Problem constants: B=2, N=2048, C=1024, H=16, D=64
// scale = D^-0.5 = 0.125 (folded into stored Q)
#define RMS_EPS 1.1920928955078125e-07f

typedef __bf16 bf16;
typedef __attribute__((ext_vector_type(8))) __bf16 bf16x8;
typedef __attribute__((ext_vector_type(4))) float f32x4;

__device__ __forceinline__ void gload16(const bf16* g, bf16* l) {
  // async global->LDS, 16B per lane; LDS dest = uniform base + lane*16
  __builtin_amdgcn_global_load_lds(
      (__attribute__((address_space(1))) void*)(g),
      (__attribute__((address_space(3))) void*)(l), 16, 0, 0);
}

// ---------------- f32 -> bf16 convert (vectorized 8/thread) ----------------
__global__ __launch_bounds__(256) void cvt_kernel(const float* __restrict__ src,
                                                  bf16* __restrict__ dst, int n8) {
  int i = blockIdx.x * 256 + threadIdx.x;
  if (i >= n8) return;
  const float4* s4 = (const float4*)src;
  float4 a = s4[i * 2], b = s4[i * 2 + 1];
  bf16x8 o;
  o[0] = (bf16)a.x; o[1] = (bf16)a.y; o[2] = (bf16)a.z; o[3] = (bf16)a.w;
  o[4] = (bf16)b.x; o[5] = (bf16)b.y; o[6] = (bf16)b.z; o[7] = (bf16)b.w;
  *(bf16x8*)(dst + i * 8) = o;
}

// ---------------- GEMM C = A * B^T, A:(M,1024) B:(Ncols,1024), both K-contig bf16
// MODE 0: write f32 C to Cout (out-proj)
// MODE 1: qkv epilogue: rms_norm Q (x0.125 folded), rms_norm K, raw V + 1/max(||v||,eps)
template <int MODE>
__global__ __launch_bounds__(256, 2) void gemm_bt(
    const bf16* __restrict__ A, const bf16* __restrict__ B,
    float* __restrict__ Cout, int Ncols,
    bf16* __restrict__ Qb, bf16* __restrict__ Kb, bf16* __restrict__ Vb,
    float* __restrict__ vninv) {
  __shared__ bf16 As[128 * 64];
  __shared__ bf16 Bs[128 * 64];
  const int tid = threadIdx.x;
  const int wave = tid >> 6, lane = tid & 63;
  const int l15 = lane & 15, g = lane >> 4;
  const int m0 = blockIdx.y * 128, n0 = blockIdx.x * 128;
  const int wr = wave >> 1, wc = wave & 1;

  f32x4 acc[4][4] = {};

  for (int k0 = 0; k0 < 1024; k0 += 64) {
    __syncthreads();
    // stage both tiles: 128 rows x 8 granules(16B), XOR-swizzled via global src (m173 pattern)
#pragma unroll
    for (int i = 0; i < 4; ++i) {
      const int gid = (i * 4 + wave) * 64 + lane;
      const int row = gid >> 3, gk = gid & 7;
      const int srcoff = k0 + ((gk ^ (row & 7)) << 3);
      gload16(A + (m0 + row) * 1024 + srcoff, As + (i * 4 + wave) * 512);
      gload16(B + (n0 + row) * 1024 + srcoff, Bs + (i * 4 + wave) * 512);
    }
    __syncthreads();
#pragma unroll
    for (int kc = 0; kc < 2; ++kc) {
      bf16x8 af[4], bfb[4];
#pragma unroll
      for (int mi = 0; mi < 4; ++mi) {
        const int row = wr * 64 + mi * 16 + l15;
        af[mi] = *(const bf16x8*)&As[row * 64 + (((kc * 4 + g) ^ (l15 & 7)) << 3)];
      }
#pragma unroll
      for (int ni = 0; ni < 4; ++ni) {
        const int row = wc * 64 + ni * 16 + l15;
        bfb[ni] = *(const bf16x8*)&Bs[row * 64 + (((kc * 4 + g) ^ (l15 & 7)) << 3)];
      }
#pragma unroll
      for (int mi = 0; mi < 4; ++mi)
#pragma unroll
        for (int ni = 0; ni < 4; ++ni)
          acc[mi][ni] = __builtin_amdgcn_mfma_f32_16x16x32_bf16(af[mi], bfb[ni], acc[mi][ni], 0, 0, 0);
    }
  }

  if (MODE == 0) {
    // plain f32 store: C/D layout col=l15, row=(l>>4)*4+reg
#pragma unroll
    for (int mi = 0; mi < 4; ++mi) {
      const int mrow = m0 + wr * 64 + mi * 16 + g * 4;
#pragma unroll
      for (int r = 0; r < 4; ++r) {
        float* cp = Cout + (long)(mrow + r) * Ncols + n0 + wc * 64 + l15;
#pragma unroll
        for (int ni = 0; ni < 4; ++ni) cp[ni * 16] = acc[mi][ni][r];
      }
    }
  } else {
    // qkv epilogue: wave's 64-col span = one (which, head). d = ni*16 + l15.
    const int ncol = n0 + wc * 64;
    const int which = ncol >> 10;
    const int h = (ncol >> 6) & 15;
#pragma unroll
    for (int mi = 0; mi < 4; ++mi) {
#pragma unroll
      for (int r = 0; r < 4; ++r) {
        float ss = 0.f;
#pragma unroll
        for (int ni = 0; ni < 4; ++ni) ss += acc[mi][ni][r] * acc[mi][ni][r];
        ss += __shfl_xor(ss, 1); ss += __shfl_xor(ss, 2);
        ss += __shfl_xor(ss, 4); ss += __shfl_xor(ss, 8);
        const int m = m0 + wr * 64 + mi * 16 + g * 4 + r;
        const int b = m >> 11, nseq = m & 2047;
        const long base = ((long)(b * 16 + h) * 2048 + nseq) * 64 + l15;
        if (which == 0) {
          const float sc = rsqrtf(ss * (1.0f / 64) + RMS_EPS) * 0.125f;
#pragma unroll
          for (int ni = 0; ni < 4; ++ni) Qb[base + ni * 16] = (bf16)(acc[mi][ni][r] * sc);
        } else if (which == 1) {
          const float sc = rsqrtf(ss * (1.0f / 64) + RMS_EPS);
#pragma unroll
          for (int ni = 0; ni < 4; ++ni) Kb[base + ni * 16] = (bf16)(acc[mi][ni][r] * sc);
        } else {
#pragma unroll
          for (int ni = 0; ni < 4; ++ni) Vb[base + ni * 16] = (bf16)acc[mi][ni][r];
          if (l15 == 0) vninv[(b * 16 + h) * 2048 + nseq] = 1.0f / fmaxf(sqrtf(ss), 1e-12f);
        }
      }
    }
  }
}

// ---------------- flash attention + xsa epilogue ----------------
// grid: 32 bh * 16 qtiles; 256 threads (4 waves), wave owns 32 q-rows (2 strips of 16)
__global__ __launch_bounds__(256, 2) void attn_kernel(
    const bf16* __restrict__ Qb, const bf16* __restrict__ Kb, const bf16* __restrict__ Vb,
    const float* __restrict__ vninv, bf16* __restrict__ Yb) {
  __shared__ bf16 Ks[64 * 64];    // [j][d], granule-swizzled by (j&7)
  __shared__ bf16 Vt[64 * 64];    // [d][j] transposed, granule-swizzled by (d>>3)
  __shared__ bf16 Ps[4][16 * 64]; // per-wave P, [q][j], granule-swizzled by (q&7)

  const int tid = threadIdx.x;
  const int wave = tid >> 6, lane = tid & 63;
  const int l15 = lane & 15, g = lane >> 4;
  const int bh = blockIdx.x >> 4, qt = blockIdx.x & 15;
  const int b = bh >> 4, h = bh & 15;
  const long off = (long)bh * 2048 * 64;
  const bf16* Qp = Qb + off;
  const bf16* Kp = Kb + off;
  const bf16* Vp = Vb + off;
  const int q0 = qt * 128;

  // Q fragments held in registers for the whole kernel
  bf16x8 qa[2][2];
#pragma unroll
  for (int s = 0; s < 2; ++s)
#pragma unroll
    for (int kc = 0; kc < 2; ++kc)
      qa[s][kc] = *(const bf16x8*)&Qp[(q0 + wave * 32 + s * 16 + l15) * 64 + kc * 32 + g * 8];

  f32x4 o[2][4] = {};
  float mrun[2][4], lrun[2][4];
#pragma unroll
  for (int s = 0; s < 2; ++s)
#pragma unroll
    for (int r = 0; r < 4; ++r) { mrun[s][r] = -__builtin_inff(); lrun[s][r] = 0.f; }

  for (int kv0 = 0; kv0 < 2048; kv0 += 64) {
    __syncthreads();
    // stage K (swizzled linear via pre-swizzled global src)
#pragma unroll
    for (int i = 0; i < 2; ++i) {
      const int gid = (i * 4 + wave) * 64 + lane;
      const int j = gid >> 3, gk = gid & 7;
      gload16(Kp + (kv0 + j) * 64 + ((gk ^ (j & 7)) << 3), Ks + (i * 4 + wave) * 512);
    }
    // stage V transposed: Vt[d][j], granule of j XOR'd with (d>>3) -> conflict-free writes
#pragma unroll
    for (int i = 0; i < 2; ++i) {
      const int gid = i * 256 + tid;
      const int j = gid >> 3, gk = gid & 7;
      const bf16x8 v8 = *(const bf16x8*)&Vp[(kv0 + j) * 64 + gk * 8];
#pragma unroll
      for (int e = 0; e < 8; ++e)
        Vt[(gk * 8 + e) * 64 + (((j >> 3) ^ gk) << 3) + (j & 7)] = v8[e];
    }
    __syncthreads();

    // K and V fragments (shared by both strips)
    bf16x8 kf[2][4], vf[2][4];
#pragma unroll
    for (int kc = 0; kc < 2; ++kc) {
#pragma unroll
      for (int jb = 0; jb < 4; ++jb)
        kf[kc][jb] = *(const bf16x8*)&Ks[(jb * 16 + l15) * 64 + (((kc * 4 + g) ^ (l15 & 7)) << 3)];
#pragma unroll
      for (int td = 0; td < 4; ++td) {
        const int d = td * 16 + l15;
        vf[kc][td] = *(const bf16x8*)&Vt[d * 64 + (((kc * 4 + g) ^ ((d >> 3) & 7)) << 3)];
      }
    }

#pragma unroll
    for (int s = 0; s < 2; ++s) {
      // S = (0.125*Qn) * Kn^T  (scale folded into stored Q)
      f32x4 sv[4] = {};
#pragma unroll
      for (int kc = 0; kc < 2; ++kc)
#pragma unroll
        for (int jb = 0; jb < 4; ++jb)
          sv[jb] = __builtin_amdgcn_mfma_f32_16x16x32_bf16(qa[s][kc], kf[kc][jb], sv[jb], 0, 0, 0);

      // online softmax; C layout: row q = 4g+r, col j = jb*16 + l15
      float pm[4], al[4], rs[4];
#pragma unroll
      for (int r = 0; r < 4; ++r)
        pm[r] = fmaxf(fmaxf(sv[0][r], sv[1][r]), fmaxf(sv[2][r], sv[3][r]));
#pragma unroll
      for (int r = 0; r < 4; ++r) {
        pm[r] = fmaxf(pm[r], __shfl_xor(pm[r], 1));
        pm[r] = fmaxf(pm[r], __shfl_xor(pm[r], 2));
        pm[r] = fmaxf(pm[r], __shfl_xor(pm[r], 4));
        pm[r] = fmaxf(pm[r], __shfl_xor(pm[r], 8));
        const float mn = fmaxf(mrun[s][r], pm[r]);
        al[r] = __expf(mrun[s][r] - mn);
        mrun[s][r] = mn;
        rs[r] = 0.f;
      }
#pragma unroll
      for (int jb = 0; jb < 4; ++jb)
#pragma unroll
        for (int r = 0; r < 4; ++r) {
          const float p = __expf(sv[jb][r] - mrun[s][r]);
          sv[jb][r] = p;
          rs[r] += p;
        }
#pragma unroll
      for (int r = 0; r < 4; ++r) {
        rs[r] += __shfl_xor(rs[r], 1);
        rs[r] += __shfl_xor(rs[r], 2);
        rs[r] += __shfl_xor(rs[r], 4);
        rs[r] += __shfl_xor(rs[r], 8);
        lrun[s][r] = lrun[s][r] * al[r] + rs[r];
      }
#pragma unroll
      for (int td = 0; td < 4; ++td)
#pragma unroll
        for (int r = 0; r < 4; ++r) o[s][td][r] *= al[r];

      // P: C-layout -> LDS (swizzled) -> A-layout
      bf16* ps = &Ps[wave][0];
#pragma unroll
      for (int jb = 0; jb < 4; ++jb)
#pragma unroll
        for (int r = 0; r < 4; ++r) {
          const int row = g * 4 + r;
          ps[row * 64 + (((jb * 2 + (l15 >> 3)) ^ (row & 7)) << 3) + (l15 & 7)] = (bf16)sv[jb][r];
        }
      bf16x8 pa[2];
#pragma unroll
      for (int kc = 0; kc < 2; ++kc)
        pa[kc] = *(const bf16x8*)&ps[l15 * 64 + (((kc * 4 + g) ^ (l15 & 7)) << 3)];
#pragma unroll
      for (int kc = 0; kc < 2; ++kc)
#pragma unroll
        for (int td = 0; td < 4; ++td)
          o[s][td] = __builtin_amdgcn_mfma_f32_16x16x32_bf16(pa[kc], vf[kc][td], o[s][td], 0, 0, 0);
    }
  }

  // epilogue: O /= l; xsa: y = O - (O . Vn) Vn; write (B,N,C) bf16
  const float* vip = vninv + bh * 2048;
#pragma unroll
  for (int s = 0; s < 2; ++s) {
#pragma unroll
    for (int r = 0; r < 4; ++r) {
      const int n = q0 + wave * 32 + s * 16 + g * 4 + r;
      const float linv = 1.0f / lrun[s][r];
      float vv[4], yv[4];
      float t = 0.f;
#pragma unroll
      for (int td = 0; td < 4; ++td) {
        vv[td] = (float)Vp[n * 64 + td * 16 + l15];
        yv[td] = o[s][td][r] * linv;
        t += yv[td] * vv[td];
      }
      t += __shfl_xor(t, 1); t += __shfl_xor(t, 2);
      t += __shfl_xor(t, 4); t += __shfl_xor(t, 8);
      const float vni = vip[n];
      const float coef = t * vni * vni;
      bf16* yp = Yb + ((long)b * 2048 + n) * 1024 + h * 64 + l15;
#pragma unroll
      for (int td = 0; td < 4; ++td) yp[td * 16] = (bf16)(yv[td] - coef * vv[td]);
    }
  }
}

// ---------------- launch ----------------
extern "C" void kernel_launch(void* const* d_in, const int* in_sizes, int n_in,
                              void* d_out, int out_size, void* d_ws, size_t ws_size,
                              hipStream_t stream) {
  (void)in_sizes; (void)n_in; (void)out_size; (void)ws_size;
  const float* x = (const float*)d_in[0];
  const float* w_qkv = (const float*)d_in[1];
  const float* w_proj = (const float*)d_in[2];
  float* out = (float*)d_out;
  char* ws = (char*)d_ws;

  // ws layout (bytes): total 50,855,936
  bf16* xb     = (bf16*)(ws);              //  8,388,608  x as bf16
  bf16* wqkvb  = (bf16*)(ws + 8388608);    //  6,291,456
  bf16* wprojb = (bf16*)(ws + 14680064);   //  2,097,152
  bf16* Qb     = (bf16*)(ws + 16777216);   //  8,388,608  (B,H,N,D) rms-normed * 0.125
  bf16* Kb     = (bf16*)(ws + 25165824);   //  8,388,608  (B,H,N,D) rms-normed
  bf16* Vb     = (bf16*)(ws + 33554432);   //  8,388,608  (B,H,N,D) raw
  float* vninv = (float*)(ws + 41943040);  //    524,288  1/max(||v||,1e-12)
  bf16* Yb     = (bf16*)(ws + 42467328);   //  8,388,608  (B,N,C) post-xsa

  cvt_kernel<<<2048, 256, 0, stream>>>(x, xb, 524288);
  cvt_kernel<<<1536, 256, 0, stream>>>(w_qkv, wqkvb, 393216);
  cvt_kernel<<<512, 256, 0, stream>>>(w_proj, wprojb, 131072);

  gemm_bt<1><<<dim3(24, 32), 256, 0, stream>>>(xb, wqkvb, nullptr, 3072,
                                               Qb, Kb, Vb, vninv);
  attn_kernel<<<512, 256, 0, stream>>>(Qb, Kb, Vb, vninv, Yb);
  gemm_bt<0><<<dim3(8, 32), 256, 0, stream>>>(Yb, wprojb, out, 1024,
                                              nullptr, nullptr, nullptr, nullptr);
}

// Round 2
// 153.991 us; speedup vs baseline: 1.2974x; 1.2974x over previous
//
#include <hip/hip_runtime.h>
#include <hip/hip_bf16.h>
#include <cstdint>

// Problem constants: B=2, N=2048, C=1024, H=16, D=64
// Q is stored pre-scaled by D^-0.5 * log2(e) so softmax runs in exp2 domain.
#define RMS_EPS 1.1920928955078125e-07f

typedef __bf16 bf16;
typedef __attribute__((ext_vector_type(8))) __bf16 bf16x8;
typedef __attribute__((ext_vector_type(4))) __bf16 bf16x4;
typedef __attribute__((ext_vector_type(4))) float f32x4;
typedef __attribute__((ext_vector_type(16))) float f32x16;
typedef unsigned int u32;
typedef __attribute__((ext_vector_type(4))) u32 u32x4;

__device__ __forceinline__ void gload16(const bf16* g, bf16* l) {
  __builtin_amdgcn_global_load_lds(
      (__attribute__((address_space(1))) void*)(g),
      (__attribute__((address_space(3))) void*)(l), 16, 0, 0);
}

__device__ __forceinline__ float fexp2(float x) {
#if __has_builtin(__builtin_amdgcn_exp2f)
  return __builtin_amdgcn_exp2f(x);
#else
  return exp2f(x);
#endif
}

__device__ __forceinline__ u32 pack2(float a, float b) {
  unsigned short xa = __builtin_bit_cast(unsigned short, (bf16)a);
  unsigned short xb = __builtin_bit_cast(unsigned short, (bf16)b);
  return (u32)xa | ((u32)xb << 16);
}

// ---------------- f32 -> bf16 convert (vectorized 8/thread) ----------------
__global__ __launch_bounds__(256) void cvt_kernel(const float* __restrict__ src,
                                                  bf16* __restrict__ dst, int n8) {
  int i = blockIdx.x * 256 + threadIdx.x;
  if (i >= n8) return;
  const float4* s4 = (const float4*)src;
  float4 a = s4[i * 2], b = s4[i * 2 + 1];
  bf16x8 o;
  o[0] = (bf16)a.x; o[1] = (bf16)a.y; o[2] = (bf16)a.z; o[3] = (bf16)a.w;
  o[4] = (bf16)b.x; o[5] = (bf16)b.y; o[6] = (bf16)b.z; o[7] = (bf16)b.w;
  *(bf16x8*)(dst + i * 8) = o;
}

// ---------------- GEMM C = A * B^T, A:(M,1024) B:(Ncols,1024), both K-contig bf16
// MODE 0: write f32 C to Cout (out-proj)
// MODE 1: qkv epilogue: rms_norm Q (x 0.125*log2e folded), rms_norm K, raw V + 1/max(||v||,eps)
template <int MODE>
__global__ __launch_bounds__(256, 2) void gemm_bt(
    const bf16* __restrict__ A, const bf16* __restrict__ B,
    float* __restrict__ Cout, int Ncols,
    bf16* __restrict__ Qb, bf16* __restrict__ Kb, bf16* __restrict__ Vb,
    float* __restrict__ vninv) {
  __shared__ bf16 As[128 * 64];
  __shared__ bf16 Bs[128 * 64];
  const int tid = threadIdx.x;
  const int wave = tid >> 6, lane = tid & 63;
  const int l15 = lane & 15, g = lane >> 4;
  const int m0 = blockIdx.y * 128, n0 = blockIdx.x * 128;
  const int wr = wave >> 1, wc = wave & 1;

  f32x4 acc[4][4] = {};

  for (int k0 = 0; k0 < 1024; k0 += 64) {
    __syncthreads();
#pragma unroll
    for (int i = 0; i < 4; ++i) {
      const int gid = (i * 4 + wave) * 64 + lane;
      const int row = gid >> 3, gk = gid & 7;
      const int srcoff = k0 + ((gk ^ (row & 7)) << 3);
      gload16(A + (m0 + row) * 1024 + srcoff, As + (i * 4 + wave) * 512);
      gload16(B + (n0 + row) * 1024 + srcoff, Bs + (i * 4 + wave) * 512);
    }
    __syncthreads();
#pragma unroll
    for (int kc = 0; kc < 2; ++kc) {
      bf16x8 af[4], bfb[4];
#pragma unroll
      for (int mi = 0; mi < 4; ++mi) {
        const int row = wr * 64 + mi * 16 + l15;
        af[mi] = *(const bf16x8*)&As[row * 64 + (((kc * 4 + g) ^ (l15 & 7)) << 3)];
      }
#pragma unroll
      for (int ni = 0; ni < 4; ++ni) {
        const int row = wc * 64 + ni * 16 + l15;
        bfb[ni] = *(const bf16x8*)&Bs[row * 64 + (((kc * 4 + g) ^ (l15 & 7)) << 3)];
      }
#pragma unroll
      for (int mi = 0; mi < 4; ++mi)
#pragma unroll
        for (int ni = 0; ni < 4; ++ni)
          acc[mi][ni] = __builtin_amdgcn_mfma_f32_16x16x32_bf16(af[mi], bfb[ni], acc[mi][ni], 0, 0, 0);
    }
  }

  if (MODE == 0) {
#pragma unroll
    for (int mi = 0; mi < 4; ++mi) {
      const int mrow = m0 + wr * 64 + mi * 16 + g * 4;
#pragma unroll
      for (int r = 0; r < 4; ++r) {
        float* cp = Cout + (long)(mrow + r) * Ncols + n0 + wc * 64 + l15;
#pragma unroll
        for (int ni = 0; ni < 4; ++ni) cp[ni * 16] = acc[mi][ni][r];
      }
    }
  } else {
    const int ncol = n0 + wc * 64;
    const int which = ncol >> 10;
    const int h = (ncol >> 6) & 15;
#pragma unroll
    for (int mi = 0; mi < 4; ++mi) {
#pragma unroll
      for (int r = 0; r < 4; ++r) {
        float ss = 0.f;
#pragma unroll
        for (int ni = 0; ni < 4; ++ni) ss += acc[mi][ni][r] * acc[mi][ni][r];
        ss += __shfl_xor(ss, 1); ss += __shfl_xor(ss, 2);
        ss += __shfl_xor(ss, 4); ss += __shfl_xor(ss, 8);
        const int m = m0 + wr * 64 + mi * 16 + g * 4 + r;
        const int b = m >> 11, nseq = m & 2047;
        const long base = ((long)(b * 16 + h) * 2048 + nseq) * 64 + l15;
        if (which == 0) {
          // fold attention scale (0.125) and log2(e) into Q
          const float sc = rsqrtf(ss * (1.0f / 64) + RMS_EPS) * (0.125f * 1.44269504088896340736f);
#pragma unroll
          for (int ni = 0; ni < 4; ++ni) Qb[base + ni * 16] = (bf16)(acc[mi][ni][r] * sc);
        } else if (which == 1) {
          const float sc = rsqrtf(ss * (1.0f / 64) + RMS_EPS);
#pragma unroll
          for (int ni = 0; ni < 4; ++ni) Kb[base + ni * 16] = (bf16)(acc[mi][ni][r] * sc);
        } else {
#pragma unroll
          for (int ni = 0; ni < 4; ++ni) Vb[base + ni * 16] = (bf16)acc[mi][ni][r];
          if (l15 == 0) vninv[(b * 16 + h) * 2048 + nseq] = 1.0f / fmaxf(sqrtf(ss), 1e-12f);
        }
      }
    }
  }
}

// ---------------- flash attention, 8 warps x 32x32 MFMA, swapped operands ----------------
// grid: 32 bh * 8 qblocks of 256 rows; 512 threads; warp owns 32 q-rows.
// All softmax state lives at q = lane&31 (both QK^T and PV are operand-swapped).
__global__ __launch_bounds__(512, 2) void attn_kernel(
    const bf16* __restrict__ Qb, const bf16* __restrict__ Kb, const bf16* __restrict__ Vb,
    const float* __restrict__ vninv, bf16* __restrict__ Yb) {
  __shared__ bf16 Ks[2][64 * 64];  // [j][d] linear, source-granule-swizzled by (j&7)
  __shared__ bf16 Vt[2][64 * 64];  // [d][j] transposed, granule-swizzled by ((d>>3)^d)&7

  const int tid = threadIdx.x;
  const int wq = tid >> 6;
  const int lane = tid & 63;
  const int l31 = lane & 31, hi = lane >> 5;
  const int bh = blockIdx.x >> 3, qb = blockIdx.x & 7;
  const int b = bh >> 4, h = bh & 15;
  const long off = (long)bh * (2048 * 64);
  const bf16* Qp = Qb + off;
  const bf16* Kp = Kb + off;
  const bf16* Vp = Vb + off;
  const int q0 = qb * 256 + wq * 32;
  const int qrow = q0 + l31;

  // Q B-frags in registers for the whole kernel: row q=l31, k = kc*16 + hi*8 + i
  bf16x8 qf[4];
#pragma unroll
  for (int kc = 0; kc < 4; ++kc)
    qf[kc] = *(const bf16x8*)&Qp[qrow * 64 + kc * 16 + hi * 8];

  f32x16 o[2] = {};              // O^T[d][q]: q = l31, d = (r&3)+8*(r>>2)+4*hi+32*dt
  float mrun = -__builtin_inff();
  float lrun = 0.f;

  // staging geometry (512 threads): row sj = tid>>3, 16B granule sgk = tid&7
  const int sj = tid >> 3, sgk = tid & 7;
  const int ksrc = sj * 64 + ((sgk ^ (sj & 7)) << 3);

  // prologue: stage kv tile 0
  gload16(Kp + ksrc, &Ks[0][wq * 512]);
  {
    bf16x8 v8 = *(const bf16x8*)&Vp[sj * 64 + sgk * 8];
#pragma unroll
    for (int e = 0; e < 8; ++e)
      Vt[0][(sgk * 8 + e) * 64 + ((wq ^ sgk ^ e) << 3) + (sj & 7)] = v8[e];
  }
  __syncthreads();

  int cur = 0;
  for (int kv0 = 0; kv0 < 2048; kv0 += 64) {
    const bool pf = (kv0 + 64) < 2048;
    bf16x8 v8;
    if (pf) {  // issue next-tile loads early; latency hides under compute (T14)
      gload16(Kp + (kv0 + 64) * 64 + ksrc, &Ks[cur ^ 1][wq * 512]);
      v8 = *(const bf16x8*)&Vp[(kv0 + 64 + sj) * 64 + sgk * 8];
    }
    const bf16* ks = &Ks[cur][0];
    const bf16* vt = &Vt[cur][0];

    // S^T = K * Q^T : lane holds S[j][q=l31], j = jt*32 + (r&3)+8*(r>>2)+4*hi
    f32x16 sv[2] = {};
    __builtin_amdgcn_s_setprio(1);
#pragma unroll
    for (int jt = 0; jt < 2; ++jt) {
      const int j = jt * 32 + l31;
#pragma unroll
      for (int kc = 0; kc < 4; ++kc) {
        bf16x8 kf = *(const bf16x8*)&ks[j * 64 + (((2 * kc + hi) ^ (j & 7)) << 3)];
        sv[jt] = __builtin_amdgcn_mfma_f32_32x32x16_bf16(kf, qf[kc], sv[jt], 0, 0, 0);
      }
    }
    __builtin_amdgcn_s_setprio(0);

    // online softmax, exp2 domain, state scalar-per-lane
    float pmax = -__builtin_inff();
#pragma unroll
    for (int jt = 0; jt < 2; ++jt)
#pragma unroll
      for (int r = 0; r < 16; ++r) pmax = fmaxf(pmax, sv[jt][r]);
    pmax = fmaxf(pmax, __shfl_xor(pmax, 32));
    const float mn = fmaxf(mrun, pmax);
    const float al = fexp2(mrun - mn);
    mrun = mn;
    float rs = 0.f;
#pragma unroll
    for (int jt = 0; jt < 2; ++jt)
#pragma unroll
      for (int r = 0; r < 16; ++r) {
        const float p = fexp2(sv[jt][r] - mn);
        sv[jt][r] = p;
        rs += p;
      }
    rs += __shfl_xor(rs, 32);
    lrun = lrun * al + rs;
#pragma unroll
    for (int dt = 0; dt < 2; ++dt)
#pragma unroll
      for (int r = 0; r < 16; ++r) o[dt][r] *= al;

    // P (C-layout, q=lane) -> bf16 A-frags via pack + half-wave register exchange.
    // word w[jt][2*rr+b] covers j = jt*32 + 8*rr + 4*hi + 2*b + {0,1}
    u32 w[2][8], pw[2][8];
#pragma unroll
    for (int jt = 0; jt < 2; ++jt)
#pragma unroll
      for (int i = 0; i < 8; ++i) {
        w[jt][i] = pack2(sv[jt][2 * i], sv[jt][2 * i + 1]);
        pw[jt][i] = __shfl_xor(w[jt][i], 32);
      }
    bf16x8 pafr[4];  // A-frag kc: row q=l31, k-local i -> j = kc*16 + hi*8 + i
#pragma unroll
    for (int kc = 0; kc < 4; ++kc) {
      const int c = kc & 1, jt = kc >> 1;
      u32x4 pv;
      pv[0] = hi ? pw[jt][4 * c + 2] : w[jt][4 * c];
      pv[1] = hi ? pw[jt][4 * c + 3] : w[jt][4 * c + 1];
      pv[2] = hi ? w[jt][4 * c + 2] : pw[jt][4 * c];
      pv[3] = hi ? w[jt][4 * c + 3] : pw[jt][4 * c + 1];
      pafr[kc] = __builtin_bit_cast(bf16x8, pv);
    }

    // O^T += V^T * P : A = Vt rows (m=d), B = P (n=q)
    __builtin_amdgcn_s_setprio(1);
#pragma unroll
    for (int dt = 0; dt < 2; ++dt) {
      const int d = dt * 32 + l31;
      const int key = ((d >> 3) ^ d) & 7;
#pragma unroll
      for (int kc = 0; kc < 4; ++kc) {
        bf16x8 vf = *(const bf16x8*)&vt[d * 64 + (((2 * kc + hi) ^ key) << 3)];
        o[dt] = __builtin_amdgcn_mfma_f32_32x32x16_bf16(vf, pafr[kc], o[dt], 0, 0, 0);
      }
    }
    __builtin_amdgcn_s_setprio(0);

    if (pf) {  // late half of async-STAGE: write prefetched V into other buffer
#pragma unroll
      for (int e = 0; e < 8; ++e)
        Vt[cur ^ 1][(sgk * 8 + e) * 64 + ((wq ^ sgk ^ e) << 3) + (sj & 7)] = v8[e];
    }
    __syncthreads();
    cur ^= 1;
  }

  // epilogue: y = O/l ; xsa: y -= (y . Vn) Vn ; store (B,N,C) bf16
  const float linv = 1.f / lrun;
  const float vni = vninv[bh * 2048 + qrow];
  const float cvn = vni * vni;
  float yv[2][16], vvf[2][16];
  float t = 0.f;
#pragma unroll
  for (int dt = 0; dt < 2; ++dt)
#pragma unroll
    for (int rr = 0; rr < 4; ++rr) {
      bf16x4 v4 = *(const bf16x4*)&Vp[qrow * 64 + dt * 32 + rr * 8 + hi * 4];
#pragma unroll
      for (int e = 0; e < 4; ++e) {
        const int r = rr * 4 + e;  // d = e + 8*rr + 4*hi + 32*dt
        const float y = o[dt][r] * linv;
        const float vx = (float)v4[e];
        yv[dt][r] = y; vvf[dt][r] = vx;
        t += y * vx;
      }
    }
  t += __shfl_xor(t, 32);
  const float coef = t * cvn;
  bf16* yp = Yb + ((long)b * 2048 + qrow) * 1024 + h * 64;
#pragma unroll
  for (int dt = 0; dt < 2; ++dt)
#pragma unroll
    for (int rr = 0; rr < 4; ++rr) {
      bf16x4 y4;
#pragma unroll
      for (int e = 0; e < 4; ++e) {
        const int r = rr * 4 + e;
        y4[e] = (bf16)(yv[dt][r] - coef * vvf[dt][r]);
      }
      *(bf16x4*)&yp[dt * 32 + rr * 8 + hi * 4] = y4;
    }
}

// ---------------- launch ----------------
extern "C" void kernel_launch(void* const* d_in, const int* in_sizes, int n_in,
                              void* d_out, int out_size, void* d_ws, size_t ws_size,
                              hipStream_t stream) {
  (void)in_sizes; (void)n_in; (void)out_size; (void)ws_size;
  const float* x = (const float*)d_in[0];
  const float* w_qkv = (const float*)d_in[1];
  const float* w_proj = (const float*)d_in[2];
  float* out = (float*)d_out;
  char* ws = (char*)d_ws;

  bf16* xb     = (bf16*)(ws);              //  8,388,608  x as bf16
  bf16* wqkvb  = (bf16*)(ws + 8388608);    //  6,291,456
  bf16* wprojb = (bf16*)(ws + 14680064);   //  2,097,152
  bf16* Qb     = (bf16*)(ws + 16777216);   //  8,388,608  (B,H,N,D) rms-normed * 0.125*log2e
  bf16* Kb     = (bf16*)(ws + 25165824);   //  8,388,608  (B,H,N,D) rms-normed
  bf16* Vb     = (bf16*)(ws + 33554432);   //  8,388,608  (B,H,N,D) raw
  float* vninv = (float*)(ws + 41943040);  //    524,288  1/max(||v||,1e-12)
  bf16* Yb     = (bf16*)(ws + 42467328);   //  8,388,608  (B,N,C) post-xsa

  cvt_kernel<<<2048, 256, 0, stream>>>(x, xb, 524288);
  cvt_kernel<<<1536, 256, 0, stream>>>(w_qkv, wqkvb, 393216);
  cvt_kernel<<<512, 256, 0, stream>>>(w_proj, wprojb, 131072);

  gemm_bt<1><<<dim3(24, 32), 256, 0, stream>>>(xb, wqkvb, nullptr, 3072,
                                               Qb, Kb, Vb, vninv);
  attn_kernel<<<256, 512, 0, stream>>>(Qb, Kb, Vb, vninv, Yb);
  gemm_bt<0><<<dim3(8, 32), 256, 0, stream>>>(Yb, wprojb, out, 1024,
                                              nullptr, nullptr, nullptr, nullptr);
}

// Round 4
// 144.268 us; speedup vs baseline: 1.3849x; 1.0674x over previous
//
#include <hip/hip_runtime.h>
#include <hip/hip_bf16.h>
#include <cstdint>

// Problem constants: B=2, N=2048, C=1024, H=16, D=64
// Q is stored pre-scaled by D^-0.5 * log2(e) so softmax runs in exp2 domain.
#define RMS_EPS 1.1920928955078125e-07f

typedef __bf16 bf16;
typedef __attribute__((ext_vector_type(8))) __bf16 bf16x8;
typedef __attribute__((ext_vector_type(4))) __bf16 bf16x4;
typedef __attribute__((ext_vector_type(4))) float f32x4;
typedef __attribute__((ext_vector_type(16))) float f32x16;
typedef unsigned int u32;
typedef __attribute__((ext_vector_type(4))) u32 u32x4;

__device__ __forceinline__ void gload16(const bf16* g, bf16* l) {
  __builtin_amdgcn_global_load_lds(
      (__attribute__((address_space(1))) void*)(g),
      (__attribute__((address_space(3))) void*)(l), 16, 0, 0);
}

__device__ __forceinline__ float fexp2(float x) {
#if __has_builtin(__builtin_amdgcn_exp2f)
  return __builtin_amdgcn_exp2f(x);
#else
  return exp2f(x);
#endif
}

__device__ __forceinline__ u32 pack2(float a, float b) {
  unsigned short xa = __builtin_bit_cast(unsigned short, (bf16)a);
  unsigned short xb = __builtin_bit_cast(unsigned short, (bf16)b);
  return (u32)xa | ((u32)xb << 16);
}

// ---------------- fused f32 -> bf16 convert for all three inputs ----------------
// granule counts: x 524288, w_qkv 393216, w_proj 131072 (total 1048576 = 4096 blocks)
__global__ __launch_bounds__(256) void cvt3_kernel(
    const float* __restrict__ x, const float* __restrict__ wq, const float* __restrict__ wp,
    bf16* __restrict__ xo, bf16* __restrict__ wqo, bf16* __restrict__ wpo) {
  int i = blockIdx.x * 256 + threadIdx.x;
  const float* s; bf16* d; int off;
  if (i < 524288) { s = x; d = xo; off = i; }
  else if (i < 917504) { s = wq; d = wqo; off = i - 524288; }
  else { s = wp; d = wpo; off = i - 917504; }
  const float4* s4 = (const float4*)s;
  float4 a = s4[off * 2], b = s4[off * 2 + 1];
  bf16x8 o;
  o[0] = (bf16)a.x; o[1] = (bf16)a.y; o[2] = (bf16)a.z; o[3] = (bf16)a.w;
  o[4] = (bf16)b.x; o[5] = (bf16)b.y; o[6] = (bf16)b.z; o[7] = (bf16)b.w;
  *(bf16x8*)(d + off * 8) = o;
}

// ---------------- GEMM C = A * B^T, A:(M,1024) B:(Ncols,1024), both K-contig bf16
// MODE 0: write f32 C to Cout (out-proj)
// MODE 1: qkv epilogue: rms_norm Q (x 0.125*log2e folded), rms_norm K, raw V + 1/max(||v||,eps)
template <int MODE>
__global__ __launch_bounds__(256, 2) void gemm_bt(
    const bf16* __restrict__ A, const bf16* __restrict__ B,
    float* __restrict__ Cout, int Ncols,
    bf16* __restrict__ Qb, bf16* __restrict__ Kb, bf16* __restrict__ Vb,
    float* __restrict__ vninv) {
  __shared__ bf16 As[128 * 64];
  __shared__ bf16 Bs[128 * 64];
  const int tid = threadIdx.x;
  const int wave = tid >> 6, lane = tid & 63;
  const int l15 = lane & 15, g = lane >> 4;
  const int m0 = blockIdx.y * 128, n0 = blockIdx.x * 128;
  const int wr = wave >> 1, wc = wave & 1;

  f32x4 acc[4][4] = {};

  for (int k0 = 0; k0 < 1024; k0 += 64) {
    __syncthreads();
#pragma unroll
    for (int i = 0; i < 4; ++i) {
      const int gid = (i * 4 + wave) * 64 + lane;
      const int row = gid >> 3, gk = gid & 7;
      const int srcoff = k0 + ((gk ^ (row & 7)) << 3);
      gload16(A + (m0 + row) * 1024 + srcoff, As + (i * 4 + wave) * 512);
      gload16(B + (n0 + row) * 1024 + srcoff, Bs + (i * 4 + wave) * 512);
    }
    __syncthreads();
#pragma unroll
    for (int kc = 0; kc < 2; ++kc) {
      bf16x8 af[4], bfb[4];
#pragma unroll
      for (int mi = 0; mi < 4; ++mi) {
        const int row = wr * 64 + mi * 16 + l15;
        af[mi] = *(const bf16x8*)&As[row * 64 + (((kc * 4 + g) ^ (l15 & 7)) << 3)];
      }
#pragma unroll
      for (int ni = 0; ni < 4; ++ni) {
        const int row = wc * 64 + ni * 16 + l15;
        bfb[ni] = *(const bf16x8*)&Bs[row * 64 + (((kc * 4 + g) ^ (l15 & 7)) << 3)];
      }
#pragma unroll
      for (int mi = 0; mi < 4; ++mi)
#pragma unroll
        for (int ni = 0; ni < 4; ++ni)
          acc[mi][ni] = __builtin_amdgcn_mfma_f32_16x16x32_bf16(af[mi], bfb[ni], acc[mi][ni], 0, 0, 0);
    }
  }

  if (MODE == 0) {
#pragma unroll
    for (int mi = 0; mi < 4; ++mi) {
      const int mrow = m0 + wr * 64 + mi * 16 + g * 4;
#pragma unroll
      for (int r = 0; r < 4; ++r) {
        float* cp = Cout + (long)(mrow + r) * Ncols + n0 + wc * 64 + l15;
#pragma unroll
        for (int ni = 0; ni < 4; ++ni) cp[ni * 16] = acc[mi][ni][r];
      }
    }
  } else {
    const int ncol = n0 + wc * 64;
    const int which = ncol >> 10;
    const int h = (ncol >> 6) & 15;
#pragma unroll
    for (int mi = 0; mi < 4; ++mi) {
#pragma unroll
      for (int r = 0; r < 4; ++r) {
        float ss = 0.f;
#pragma unroll
        for (int ni = 0; ni < 4; ++ni) ss += acc[mi][ni][r] * acc[mi][ni][r];
        ss += __shfl_xor(ss, 1); ss += __shfl_xor(ss, 2);
        ss += __shfl_xor(ss, 4); ss += __shfl_xor(ss, 8);
        const int m = m0 + wr * 64 + mi * 16 + g * 4 + r;
        const int b = m >> 11, nseq = m & 2047;
        const long base = ((long)(b * 16 + h) * 2048 + nseq) * 64 + l15;
        if (which == 0) {
          const float sc = rsqrtf(ss * (1.0f / 64) + RMS_EPS) * (0.125f * 1.44269504088896340736f);
#pragma unroll
          for (int ni = 0; ni < 4; ++ni) Qb[base + ni * 16] = (bf16)(acc[mi][ni][r] * sc);
        } else if (which == 1) {
          const float sc = rsqrtf(ss * (1.0f / 64) + RMS_EPS);
#pragma unroll
          for (int ni = 0; ni < 4; ++ni) Kb[base + ni * 16] = (bf16)(acc[mi][ni][r] * sc);
        } else {
#pragma unroll
          for (int ni = 0; ni < 4; ++ni) Vb[base + ni * 16] = (bf16)acc[mi][ni][r];
          if (l15 == 0) vninv[(b * 16 + h) * 2048 + nseq] = 1.0f / fmaxf(sqrtf(ss), 1e-12f);
        }
      }
    }
  }
}

// ---------------- flash attention, 4 warps x 32x32 MFMA, swapped operands ----------------
// grid: 32 bh * 16 qblocks of 128 rows; 256 threads; warp owns 32 q-rows.
// 512 blocks = 2 blocks/CU so barrier drains overlap across blocks.
__global__ __launch_bounds__(256, 2) void attn_kernel(
    const bf16* __restrict__ Qb, const bf16* __restrict__ Kb, const bf16* __restrict__ Vb,
    const float* __restrict__ vninv, bf16* __restrict__ Yb) {
  __shared__ bf16 Ks[2][64 * 64];  // [j][d] linear, source-granule-swizzled by (j&7)
  __shared__ bf16 Vt[2][64 * 64];  // [d][j] transposed, granule-swizzled by ((d>>3)^d)&7

  const int tid = threadIdx.x;
  const int wq = tid >> 6;
  const int lane = tid & 63;
  const int l31 = lane & 31, hi = lane >> 5;
  const int bh = blockIdx.x >> 4, qb = blockIdx.x & 15;
  const int b = bh >> 4, h = bh & 15;
  const long off = (long)bh * (2048 * 64);
  const bf16* Qp = Qb + off;
  const bf16* Kp = Kb + off;
  const bf16* Vp = Vb + off;
  const int qrow = qb * 128 + wq * 32 + l31;

  // Q B-frags in registers for the whole kernel: row q=l31, k = kc*16 + hi*8 + i
  bf16x8 qf[4];
#pragma unroll
  for (int kc = 0; kc < 4; ++kc)
    qf[kc] = *(const bf16x8*)&Qp[qrow * 64 + kc * 16 + hi * 8];

  f32x16 o[2] = {};  // O^T[d][q]: q = l31, d = (r&3)+8*(r>>2)+4*hi+32*dt
  float mrun = -__builtin_inff();
  float lrun = 0.f;

  // K staging: 2 gload16 per thread (wave-uniform LDS chunk)
  const int kj = (lane >> 3), kgk = lane & 7;
  // prologue: stage kv tile 0
#pragma unroll
  for (int i = 0; i < 2; ++i) {
    const int chunk = i * 4 + wq;
    const int j = chunk * 8 + kj;
    gload16(Kp + j * 64 + ((kgk ^ (j & 7)) << 3), &Ks[0][chunk * 512]);
  }
#pragma unroll
  for (int i = 0; i < 2; ++i) {
    const int gid = i * 256 + tid;
    const int j = gid >> 3, gk = gid & 7, jg = gid >> 6;
    bf16x8 v8 = *(const bf16x8*)&Vp[j * 64 + gk * 8];
#pragma unroll
    for (int e = 0; e < 8; ++e)
      Vt[0][(gk * 8 + e) * 64 + ((jg ^ gk ^ e) << 3) + (j & 7)] = v8[e];
  }
  __syncthreads();

  int cur = 0;
  for (int kv0 = 0; kv0 < 2048; kv0 += 64) {
    const bool pf = (kv0 + 64) < 2048;
    bf16x8 v8[2];
    if (pf) {  // async-STAGE: issue next-tile loads early (T14)
#pragma unroll
      for (int i = 0; i < 2; ++i) {
        const int chunk = i * 4 + wq;
        const int j = chunk * 8 + kj;
        gload16(Kp + (kv0 + 64 + j) * 64 + ((kgk ^ (j & 7)) << 3), &Ks[cur ^ 1][chunk * 512]);
      }
#pragma unroll
      for (int i = 0; i < 2; ++i) {
        const int gid = i * 256 + tid;
        v8[i] = *(const bf16x8*)&Vp[(kv0 + 64 + (gid >> 3)) * 64 + (gid & 7) * 8];
      }
    }
    const bf16* ks = &Ks[cur][0];
    const bf16* vt = &Vt[cur][0];

    // S^T = K * Q^T : lane holds S[j][q=l31], j = jt*32 + (r&3)+8*(r>>2)+4*hi
    f32x16 sv[2] = {};
    __builtin_amdgcn_s_setprio(1);
#pragma unroll
    for (int jt = 0; jt < 2; ++jt) {
      const int j = jt * 32 + l31;
#pragma unroll
      for (int kc = 0; kc < 4; ++kc) {
        bf16x8 kf = *(const bf16x8*)&ks[j * 64 + (((2 * kc + hi) ^ (j & 7)) << 3)];
        sv[jt] = __builtin_amdgcn_mfma_f32_32x32x16_bf16(kf, qf[kc], sv[jt], 0, 0, 0);
      }
    }
    __builtin_amdgcn_s_setprio(0);

    // ---- online softmax (exp2 domain), tree reductions, defer-max (T13) ----
    float mx[16];
#pragma unroll
    for (int r = 0; r < 16; ++r) mx[r] = fmaxf(sv[0][r], sv[1][r]);
#pragma unroll
    for (int s2 = 8; s2 > 0; s2 >>= 1)
#pragma unroll
      for (int r = 0; r < s2; ++r) mx[r] = fmaxf(mx[r], mx[r + s2]);
    float pmax = fmaxf(mx[0], __shfl_xor(mx[0], 32));

    if (!__all(pmax <= mrun + 8.f)) {  // rescale only when max grew past threshold
      const float mn = fmaxf(mrun, pmax);
      const float al = fexp2(mrun - mn);
      mrun = mn;
      lrun *= al;
#pragma unroll
      for (int dt = 0; dt < 2; ++dt)
#pragma unroll
        for (int r = 0; r < 16; ++r) o[dt][r] *= al;
    }

#pragma unroll
    for (int jt = 0; jt < 2; ++jt)
#pragma unroll
      for (int r = 0; r < 16; ++r) sv[jt][r] = fexp2(sv[jt][r] - mrun);
    float sm[16];
#pragma unroll
    for (int r = 0; r < 16; ++r) sm[r] = sv[0][r] + sv[1][r];
#pragma unroll
    for (int s2 = 8; s2 > 0; s2 >>= 1)
#pragma unroll
      for (int r = 0; r < s2; ++r) sm[r] += sm[r + s2];
    lrun += sm[0] + __shfl_xor(sm[0], 32);

    // ---- P (C-layout, q=lane) -> bf16 A-frags: pack + half-wave exchange ----
    // word w[jt][2*rr+c2] covers j = jt*32 + 8*rr + 4*hi + 2*c2 + {0,1}
    // (proven R2 shfl_xor form; permlane32_swap variant deferred — operand
    //  semantics are vdst.hi-lanes <-> vsrc.lo-lanes, to be A/B'd later)
    u32 w[2][8], pw[2][8];
#pragma unroll
    for (int jt = 0; jt < 2; ++jt)
#pragma unroll
      for (int i = 0; i < 8; ++i) {
        w[jt][i] = pack2(sv[jt][2 * i], sv[jt][2 * i + 1]);
        pw[jt][i] = __shfl_xor(w[jt][i], 32);
      }
    bf16x8 pafr[4];  // B-frag kc: col q=l31, k-local i -> j = kc*16 + hi*8 + i
#pragma unroll
    for (int kc = 0; kc < 4; ++kc) {
      const int c = kc & 1, jt = kc >> 1;
      u32x4 pv;
      pv[0] = hi ? pw[jt][4 * c + 2] : w[jt][4 * c];
      pv[1] = hi ? pw[jt][4 * c + 3] : w[jt][4 * c + 1];
      pv[2] = hi ? w[jt][4 * c + 2] : pw[jt][4 * c];
      pv[3] = hi ? w[jt][4 * c + 3] : pw[jt][4 * c + 1];
      pafr[kc] = __builtin_bit_cast(bf16x8, pv);
    }

    // O^T += V^T * P : A = Vt rows (m=d), B = P (n=q)
    __builtin_amdgcn_s_setprio(1);
#pragma unroll
    for (int dt = 0; dt < 2; ++dt) {
      const int d = dt * 32 + l31;
      const int key = ((d >> 3) ^ d) & 7;
#pragma unroll
      for (int kc = 0; kc < 4; ++kc) {
        bf16x8 vf = *(const bf16x8*)&vt[d * 64 + (((2 * kc + hi) ^ key) << 3)];
        o[dt] = __builtin_amdgcn_mfma_f32_32x32x16_bf16(vf, pafr[kc], o[dt], 0, 0, 0);
      }
    }
    __builtin_amdgcn_s_setprio(0);

    if (pf) {  // late half of async-STAGE: write prefetched V into other buffer
#pragma unroll
      for (int i = 0; i < 2; ++i) {
        const int gid = i * 256 + tid;
        const int j = gid >> 3, gk = gid & 7, jg = gid >> 6;
#pragma unroll
        for (int e = 0; e < 8; ++e)
          Vt[cur ^ 1][(gk * 8 + e) * 64 + ((jg ^ gk ^ e) << 3) + (j & 7)] = v8[i][e];
      }
    }
    __syncthreads();
    cur ^= 1;
  }

  // epilogue: y = O/l ; xsa: y -= (y . Vn) Vn ; store (B,N,C) bf16
  const float linv = 1.f / lrun;
  const float vni = vninv[bh * 2048 + qrow];
  const float cvn = vni * vni;
  float yv[2][16], vvf[2][16];
  float t = 0.f;
#pragma unroll
  for (int dt = 0; dt < 2; ++dt)
#pragma unroll
    for (int rr = 0; rr < 4; ++rr) {
      bf16x4 v4 = *(const bf16x4*)&Vp[qrow * 64 + dt * 32 + rr * 8 + hi * 4];
#pragma unroll
      for (int e = 0; e < 4; ++e) {
        const int r = rr * 4 + e;  // d = e + 8*rr + 4*hi + 32*dt
        const float y = o[dt][r] * linv;
        const float vx = (float)v4[e];
        yv[dt][r] = y; vvf[dt][r] = vx;
        t += y * vx;
      }
    }
  t += __shfl_xor(t, 32);
  const float coef = t * cvn;
  bf16* yp = Yb + ((long)b * 2048 + qrow) * 1024 + h * 64;
#pragma unroll
  for (int dt = 0; dt < 2; ++dt)
#pragma unroll
    for (int rr = 0; rr < 4; ++rr) {
      bf16x4 y4;
#pragma unroll
      for (int e = 0; e < 4; ++e) {
        const int r = rr * 4 + e;
        y4[e] = (bf16)(yv[dt][r] - coef * vvf[dt][r]);
      }
      *(bf16x4*)&yp[dt * 32 + rr * 8 + hi * 4] = y4;
    }
}

// ---------------- launch ----------------
extern "C" void kernel_launch(void* const* d_in, const int* in_sizes, int n_in,
                              void* d_out, int out_size, void* d_ws, size_t ws_size,
                              hipStream_t stream) {
  (void)in_sizes; (void)n_in; (void)out_size; (void)ws_size;
  const float* x = (const float*)d_in[0];
  const float* w_qkv = (const float*)d_in[1];
  const float* w_proj = (const float*)d_in[2];
  float* out = (float*)d_out;
  char* ws = (char*)d_ws;

  bf16* xb     = (bf16*)(ws);              //  8,388,608  x as bf16
  bf16* wqkvb  = (bf16*)(ws + 8388608);    //  6,291,456
  bf16* wprojb = (bf16*)(ws + 14680064);   //  2,097,152
  bf16* Qb     = (bf16*)(ws + 16777216);   //  8,388,608  (B,H,N,D) rms-normed * 0.125*log2e
  bf16* Kb     = (bf16*)(ws + 25165824);   //  8,388,608  (B,H,N,D) rms-normed
  bf16* Vb     = (bf16*)(ws + 33554432);   //  8,388,608  (B,H,N,D) raw
  float* vninv = (float*)(ws + 41943040);  //    524,288  1/max(||v||,1e-12)
  bf16* Yb     = (bf16*)(ws + 42467328);   //  8,388,608  (B,N,C) post-xsa

  cvt3_kernel<<<4096, 256, 0, stream>>>(x, w_qkv, w_proj, xb, wqkvb, wprojb);

  gemm_bt<1><<<dim3(24, 32), 256, 0, stream>>>(xb, wqkvb, nullptr, 3072,
                                               Qb, Kb, Vb, vninv);
  attn_kernel<<<512, 256, 0, stream>>>(Qb, Kb, Vb, vninv, Yb);
  gemm_bt<0><<<dim3(8, 32), 256, 0, stream>>>(Yb, wprojb, out, 1024,
                                              nullptr, nullptr, nullptr, nullptr);
}

// Round 6
// 139.669 us; speedup vs baseline: 1.4305x; 1.0329x over previous
//
#include <hip/hip_runtime.h>
#include <hip/hip_bf16.h>
#include <cstdint>

// Problem constants: B=2, N=2048, C=1024, H=16, D=64
// Q is stored pre-scaled by D^-0.5 * log2(e) so softmax runs in exp2 domain.
#define RMS_EPS 1.1920928955078125e-07f

typedef __bf16 bf16;
typedef __attribute__((ext_vector_type(8))) __bf16 bf16x8;
typedef __attribute__((ext_vector_type(4))) __bf16 bf16x4;
typedef __attribute__((ext_vector_type(4))) float f32x4;
typedef __attribute__((ext_vector_type(16))) float f32x16;
typedef unsigned int u32;
typedef __attribute__((ext_vector_type(4))) u32 u32x4;

__device__ __forceinline__ void gload16(const bf16* g, bf16* l) {
  __builtin_amdgcn_global_load_lds(
      (__attribute__((address_space(1))) void*)(g),
      (__attribute__((address_space(3))) void*)(l), 16, 0, 0);
}

__device__ __forceinline__ float fexp2(float x) {
#if __has_builtin(__builtin_amdgcn_exp2f)
  return __builtin_amdgcn_exp2f(x);
#else
  return exp2f(x);
#endif
}

__device__ __forceinline__ u32 pack2(float a, float b) {
  unsigned short xa = __builtin_bit_cast(unsigned short, (bf16)a);
  unsigned short xb = __builtin_bit_cast(unsigned short, (bf16)b);
  return (u32)xa | ((u32)xb << 16);
}

// ---------------- fused f32 -> bf16 convert for all three inputs ----------------
__global__ __launch_bounds__(256) void cvt3_kernel(
    const float* __restrict__ x, const float* __restrict__ wq, const float* __restrict__ wp,
    bf16* __restrict__ xo, bf16* __restrict__ wqo, bf16* __restrict__ wpo) {
  int i = blockIdx.x * 256 + threadIdx.x;
  const float* s; bf16* d; int off;
  if (i < 524288) { s = x; d = xo; off = i; }
  else if (i < 917504) { s = wq; d = wqo; off = i - 524288; }
  else { s = wp; d = wpo; off = i - 917504; }
  const float4* s4 = (const float4*)s;
  float4 a = s4[off * 2], b = s4[off * 2 + 1];
  bf16x8 o;
  o[0] = (bf16)a.x; o[1] = (bf16)a.y; o[2] = (bf16)a.z; o[3] = (bf16)a.w;
  o[4] = (bf16)b.x; o[5] = (bf16)b.y; o[6] = (bf16)b.z; o[7] = (bf16)b.w;
  *(bf16x8*)(d + off * 8) = o;
}

// ---------------- GEMM C = A * B^T, A:(M,1024) B:(Ncols,1024), both K-contig bf16
// T1: XCD-aware block swizzle (nwg % 8 == 0 for both instantiations -> bijective)
template <int MODE>
__global__ __launch_bounds__(256, 2) void gemm_bt(
    const bf16* __restrict__ A, const bf16* __restrict__ B,
    float* __restrict__ Cout, int Ncols,
    bf16* __restrict__ Qb, bf16* __restrict__ Kb, bf16* __restrict__ Vb,
    float* __restrict__ vninv) {
  __shared__ bf16 As[128 * 64];
  __shared__ bf16 Bs[128 * 64];
  const int tid = threadIdx.x;
  const int wave = tid >> 6, lane = tid & 63;
  const int l15 = lane & 15, g = lane >> 4;
  // XCD swizzle: dispatch d -> tile (d%8)*(nwg/8) + d/8 (contiguous tiles per XCD)
  const int nwg = gridDim.x * gridDim.y;
  const int wg0 = blockIdx.y * gridDim.x + blockIdx.x;
  const int wg = (wg0 & 7) * (nwg >> 3) + (wg0 >> 3);
  const int m0 = (wg / gridDim.x) * 128, n0 = (wg % gridDim.x) * 128;
  const int wr = wave >> 1, wc = wave & 1;

  f32x4 acc[4][4] = {};

  for (int k0 = 0; k0 < 1024; k0 += 64) {
    __syncthreads();
#pragma unroll
    for (int i = 0; i < 4; ++i) {
      const int gid = (i * 4 + wave) * 64 + lane;
      const int row = gid >> 3, gk = gid & 7;
      const int srcoff = k0 + ((gk ^ (row & 7)) << 3);
      gload16(A + (m0 + row) * 1024 + srcoff, As + (i * 4 + wave) * 512);
      gload16(B + (n0 + row) * 1024 + srcoff, Bs + (i * 4 + wave) * 512);
    }
    __syncthreads();
#pragma unroll
    for (int kc = 0; kc < 2; ++kc) {
      bf16x8 af[4], bfb[4];
#pragma unroll
      for (int mi = 0; mi < 4; ++mi) {
        const int row = wr * 64 + mi * 16 + l15;
        af[mi] = *(const bf16x8*)&As[row * 64 + (((kc * 4 + g) ^ (l15 & 7)) << 3)];
      }
#pragma unroll
      for (int ni = 0; ni < 4; ++ni) {
        const int row = wc * 64 + ni * 16 + l15;
        bfb[ni] = *(const bf16x8*)&Bs[row * 64 + (((kc * 4 + g) ^ (l15 & 7)) << 3)];
      }
#pragma unroll
      for (int mi = 0; mi < 4; ++mi)
#pragma unroll
        for (int ni = 0; ni < 4; ++ni)
          acc[mi][ni] = __builtin_amdgcn_mfma_f32_16x16x32_bf16(af[mi], bfb[ni], acc[mi][ni], 0, 0, 0);
    }
  }

  if (MODE == 0) {
#pragma unroll
    for (int mi = 0; mi < 4; ++mi) {
      const int mrow = m0 + wr * 64 + mi * 16 + g * 4;
#pragma unroll
      for (int r = 0; r < 4; ++r) {
        float* cp = Cout + (long)(mrow + r) * Ncols + n0 + wc * 64 + l15;
#pragma unroll
        for (int ni = 0; ni < 4; ++ni) cp[ni * 16] = acc[mi][ni][r];
      }
    }
  } else {
    const int ncol = n0 + wc * 64;
    const int which = ncol >> 10;
    const int h = (ncol >> 6) & 15;
#pragma unroll
    for (int mi = 0; mi < 4; ++mi) {
#pragma unroll
      for (int r = 0; r < 4; ++r) {
        float ss = 0.f;
#pragma unroll
        for (int ni = 0; ni < 4; ++ni) ss += acc[mi][ni][r] * acc[mi][ni][r];
        ss += __shfl_xor(ss, 1); ss += __shfl_xor(ss, 2);
        ss += __shfl_xor(ss, 4); ss += __shfl_xor(ss, 8);
        const int m = m0 + wr * 64 + mi * 16 + g * 4 + r;
        const int b = m >> 11, nseq = m & 2047;
        const long base = ((long)(b * 16 + h) * 2048 + nseq) * 64 + l15;
        if (which == 0) {
          const float sc = rsqrtf(ss * (1.0f / 64) + RMS_EPS) * (0.125f * 1.44269504088896340736f);
#pragma unroll
          for (int ni = 0; ni < 4; ++ni) Qb[base + ni * 16] = (bf16)(acc[mi][ni][r] * sc);
        } else if (which == 1) {
          const float sc = rsqrtf(ss * (1.0f / 64) + RMS_EPS);
#pragma unroll
          for (int ni = 0; ni < 4; ++ni) Kb[base + ni * 16] = (bf16)(acc[mi][ni][r] * sc);
        } else {
#pragma unroll
          for (int ni = 0; ni < 4; ++ni) Vb[base + ni * 16] = (bf16)acc[mi][ni][r];
          if (l15 == 0) vninv[(b * 16 + h) * 2048 + nseq] = 1.0f / fmaxf(sqrtf(ss), 1e-12f);
        }
      }
    }
  }
}

// ---------------- flash attention, 4 warps x 32x32 MFMA, swapped operands ----------------
// grid: 32 bh * 16 qblocks of 128 rows; 256 threads; warp owns 32 q-rows.
// T1: XCD swizzle so the 16 q-blocks of one bh land on one XCD (K/V = 512KB << 4MB L2).
// (attn body = proven R4 code; R5's tr_read+permlane experiments reverted)
__global__ __launch_bounds__(256, 2) void attn_kernel(
    const bf16* __restrict__ Qb, const bf16* __restrict__ Kb, const bf16* __restrict__ Vb,
    const float* __restrict__ vninv, bf16* __restrict__ Yb) {
  __shared__ bf16 Ks[2][64 * 64];  // [j][d] linear, source-granule-swizzled by (j&7)
  __shared__ bf16 Vt[2][64 * 64];  // [d][j] transposed, granule-swizzled by ((d>>3)^d)&7

  const int tid = threadIdx.x;
  const int wq = tid >> 6;
  const int lane = tid & 63;
  const int l31 = lane & 31, hi = lane >> 5;
  // XCD swizzle (512 blocks, 512 % 8 == 0 -> bijective): XCD k gets bh 4k..4k+3 complete.
  const int wg = (blockIdx.x & 7) * (gridDim.x >> 3) + (blockIdx.x >> 3);
  const int bh = wg >> 4, qb = wg & 15;
  const int b = bh >> 4, h = bh & 15;
  const long off = (long)bh * (2048 * 64);
  const bf16* Qp = Qb + off;
  const bf16* Kp = Kb + off;
  const bf16* Vp = Vb + off;
  const int qrow = qb * 128 + wq * 32 + l31;

  // Q B-frags in registers for the whole kernel: row q=l31, k = kc*16 + hi*8 + i
  bf16x8 qf[4];
#pragma unroll
  for (int kc = 0; kc < 4; ++kc)
    qf[kc] = *(const bf16x8*)&Qp[qrow * 64 + kc * 16 + hi * 8];

  f32x16 o[2] = {};  // O^T[d][q]: q = l31, d = (r&3)+8*(r>>2)+4*hi+32*dt
  float mrun = -__builtin_inff();
  float lrun = 0.f;

  // K staging: 2 gload16 per thread (wave-uniform LDS chunk)
  const int kj = lane >> 3, kgk = lane & 7;
  // prologue: stage kv tile 0
#pragma unroll
  for (int i = 0; i < 2; ++i) {
    const int chunk = i * 4 + wq;
    const int j = chunk * 8 + kj;
    gload16(Kp + j * 64 + ((kgk ^ (j & 7)) << 3), &Ks[0][chunk * 512]);
  }
#pragma unroll
  for (int i = 0; i < 2; ++i) {
    const int gid = i * 256 + tid;
    const int j = gid >> 3, gk = gid & 7, jg = gid >> 6;
    bf16x8 v8 = *(const bf16x8*)&Vp[j * 64 + gk * 8];
#pragma unroll
    for (int e = 0; e < 8; ++e)
      Vt[0][(gk * 8 + e) * 64 + ((jg ^ gk ^ e) << 3) + (j & 7)] = v8[e];
  }
  __syncthreads();

  int cur = 0;
  for (int kv0 = 0; kv0 < 2048; kv0 += 64) {
    const bool pf = (kv0 + 64) < 2048;
    bf16x8 v8[2];
    if (pf) {  // async-STAGE: issue next-tile loads early (T14)
#pragma unroll
      for (int i = 0; i < 2; ++i) {
        const int chunk = i * 4 + wq;
        const int j = chunk * 8 + kj;
        gload16(Kp + (kv0 + 64 + j) * 64 + ((kgk ^ (j & 7)) << 3), &Ks[cur ^ 1][chunk * 512]);
      }
#pragma unroll
      for (int i = 0; i < 2; ++i) {
        const int gid = i * 256 + tid;
        v8[i] = *(const bf16x8*)&Vp[(kv0 + 64 + (gid >> 3)) * 64 + (gid & 7) * 8];
      }
    }
    const bf16* ks = &Ks[cur][0];
    const bf16* vt = &Vt[cur][0];

    // S^T = K * Q^T : lane holds S[j][q=l31], j = jt*32 + (r&3)+8*(r>>2)+4*hi
    f32x16 sv[2] = {};
    __builtin_amdgcn_s_setprio(1);
#pragma unroll
    for (int jt = 0; jt < 2; ++jt) {
      const int j = jt * 32 + l31;
#pragma unroll
      for (int kc = 0; kc < 4; ++kc) {
        bf16x8 kf = *(const bf16x8*)&ks[j * 64 + (((2 * kc + hi) ^ (j & 7)) << 3)];
        sv[jt] = __builtin_amdgcn_mfma_f32_32x32x16_bf16(kf, qf[kc], sv[jt], 0, 0, 0);
      }
    }
    __builtin_amdgcn_s_setprio(0);

    // ---- online softmax (exp2 domain), tree reductions, defer-max (T13) ----
    float mx[16];
#pragma unroll
    for (int r = 0; r < 16; ++r) mx[r] = fmaxf(sv[0][r], sv[1][r]);
#pragma unroll
    for (int s2 = 8; s2 > 0; s2 >>= 1)
#pragma unroll
      for (int r = 0; r < s2; ++r) mx[r] = fmaxf(mx[r], mx[r + s2]);
    float pmax = fmaxf(mx[0], __shfl_xor(mx[0], 32));

    if (!__all(pmax <= mrun + 8.f)) {  // rescale only when max grew past threshold
      const float mn = fmaxf(mrun, pmax);
      const float al = fexp2(mrun - mn);
      mrun = mn;
      lrun *= al;
#pragma unroll
      for (int dt = 0; dt < 2; ++dt)
#pragma unroll
        for (int r = 0; r < 16; ++r) o[dt][r] *= al;
    }

#pragma unroll
    for (int jt = 0; jt < 2; ++jt)
#pragma unroll
      for (int r = 0; r < 16; ++r) sv[jt][r] = fexp2(sv[jt][r] - mrun);
    float sm[16];
#pragma unroll
    for (int r = 0; r < 16; ++r) sm[r] = sv[0][r] + sv[1][r];
#pragma unroll
    for (int s2 = 8; s2 > 0; s2 >>= 1)
#pragma unroll
      for (int r = 0; r < s2; ++r) sm[r] += sm[r + s2];
    lrun += sm[0] + __shfl_xor(sm[0], 32);

    // ---- P (C-layout, q=lane) -> bf16 B-frags: pack + half-wave exchange ----
    // word w[jt][2*rr+c2] covers j = jt*32 + 8*rr + 4*hi + 2*c2 + {0,1}
    u32 w[2][8], pw[2][8];
#pragma unroll
    for (int jt = 0; jt < 2; ++jt)
#pragma unroll
      for (int i = 0; i < 8; ++i) {
        w[jt][i] = pack2(sv[jt][2 * i], sv[jt][2 * i + 1]);
        pw[jt][i] = __shfl_xor(w[jt][i], 32);
      }
    bf16x8 pafr[4];  // B-frag kc: col q=l31, k-local i -> j = kc*16 + hi*8 + i
#pragma unroll
    for (int kc = 0; kc < 4; ++kc) {
      const int c = kc & 1, jt = kc >> 1;
      u32x4 pv;
      pv[0] = hi ? pw[jt][4 * c + 2] : w[jt][4 * c];
      pv[1] = hi ? pw[jt][4 * c + 3] : w[jt][4 * c + 1];
      pv[2] = hi ? w[jt][4 * c + 2] : pw[jt][4 * c];
      pv[3] = hi ? w[jt][4 * c + 3] : pw[jt][4 * c + 1];
      pafr[kc] = __builtin_bit_cast(bf16x8, pv);
    }

    // O^T += V^T * P : A = Vt rows (m=d), B = P (n=q)
    __builtin_amdgcn_s_setprio(1);
#pragma unroll
    for (int dt = 0; dt < 2; ++dt) {
      const int d = dt * 32 + l31;
      const int key = ((d >> 3) ^ d) & 7;
#pragma unroll
      for (int kc = 0; kc < 4; ++kc) {
        bf16x8 vf = *(const bf16x8*)&vt[d * 64 + (((2 * kc + hi) ^ key) << 3)];
        o[dt] = __builtin_amdgcn_mfma_f32_32x32x16_bf16(vf, pafr[kc], o[dt], 0, 0, 0);
      }
    }
    __builtin_amdgcn_s_setprio(0);

    if (pf) {  // late half of async-STAGE: write prefetched V into other buffer
#pragma unroll
      for (int i = 0; i < 2; ++i) {
        const int gid = i * 256 + tid;
        const int j = gid >> 3, gk = gid & 7, jg = gid >> 6;
#pragma unroll
        for (int e = 0; e < 8; ++e)
          Vt[cur ^ 1][(gk * 8 + e) * 64 + ((jg ^ gk ^ e) << 3) + (j & 7)] = v8[i][e];
      }
    }
    __syncthreads();
    cur ^= 1;
  }

  // epilogue: y = O/l ; xsa: y -= (y . Vn) Vn ; store (B,N,C) bf16
  const float linv = 1.f / lrun;
  const float vni = vninv[bh * 2048 + qrow];
  const float cvn = vni * vni;
  float yv[2][16], vvf[2][16];
  float t = 0.f;
#pragma unroll
  for (int dt = 0; dt < 2; ++dt)
#pragma unroll
    for (int rr = 0; rr < 4; ++rr) {
      bf16x4 v4 = *(const bf16x4*)&Vp[qrow * 64 + dt * 32 + rr * 8 + hi * 4];
#pragma unroll
      for (int e = 0; e < 4; ++e) {
        const int r = rr * 4 + e;  // d = e + 8*rr + 4*hi + 32*dt
        const float y = o[dt][r] * linv;
        const float vx = (float)v4[e];
        yv[dt][r] = y; vvf[dt][r] = vx;
        t += y * vx;
      }
    }
  t += __shfl_xor(t, 32);
  const float coef = t * cvn;
  bf16* yp = Yb + ((long)b * 2048 + qrow) * 1024 + h * 64;
#pragma unroll
  for (int dt = 0; dt < 2; ++dt)
#pragma unroll
    for (int rr = 0; rr < 4; ++rr) {
      bf16x4 y4;
#pragma unroll
      for (int e = 0; e < 4; ++e) {
        const int r = rr * 4 + e;
        y4[e] = (bf16)(yv[dt][r] - coef * vvf[dt][r]);
      }
      *(bf16x4*)&yp[dt * 32 + rr * 8 + hi * 4] = y4;
    }
}

// ---------------- launch ----------------
extern "C" void kernel_launch(void* const* d_in, const int* in_sizes, int n_in,
                              void* d_out, int out_size, void* d_ws, size_t ws_size,
                              hipStream_t stream) {
  (void)in_sizes; (void)n_in; (void)out_size; (void)ws_size;
  const float* x = (const float*)d_in[0];
  const float* w_qkv = (const float*)d_in[1];
  const float* w_proj = (const float*)d_in[2];
  float* out = (float*)d_out;
  char* ws = (char*)d_ws;

  bf16* xb     = (bf16*)(ws);              //  8,388,608  x as bf16
  bf16* wqkvb  = (bf16*)(ws + 8388608);    //  6,291,456
  bf16* wprojb = (bf16*)(ws + 14680064);   //  2,097,152
  bf16* Qb     = (bf16*)(ws + 16777216);   //  8,388,608  (B,H,N,D) rms-normed * 0.125*log2e
  bf16* Kb     = (bf16*)(ws + 25165824);   //  8,388,608  (B,H,N,D) rms-normed
  bf16* Vb     = (bf16*)(ws + 33554432);   //  8,388,608  (B,H,N,D) raw
  float* vninv = (float*)(ws + 41943040);  //    524,288  1/max(||v||,1e-12)
  bf16* Yb     = (bf16*)(ws + 42467328);   //  8,388,608  (B,N,C) post-xsa

  cvt3_kernel<<<4096, 256, 0, stream>>>(x, w_qkv, w_proj, xb, wqkvb, wprojb);

  gemm_bt<1><<<dim3(24, 32), 256, 0, stream>>>(xb, wqkvb, nullptr, 3072,
                                               Qb, Kb, Vb, vninv);
  attn_kernel<<<512, 256, 0, stream>>>(Qb, Kb, Vb, vninv, Yb);
  gemm_bt<0><<<dim3(8, 32), 256, 0, stream>>>(Yb, wprojb, out, 1024,
                                              nullptr, nullptr, nullptr, nullptr);
}